// Round 8
// baseline (344.796 us; speedup 1.0000x reference)
//
#include <hip/hip_runtime.h>
#include <hip/hip_cooperative_groups.h>
#include <hip/hip_fp16.h>
#include <stdint.h>

namespace cg = cooperative_groups;

#define N_NODES   4096
#define N_EDGES   128
#define D_X       128
#define PE_DIM    64
#define NUM_WALKS 10
#define WALK_LEN  5
#define N_WALKS_TOT (N_NODES * NUM_WALKS)   /* 40960 */
#define OUT_COLS  (D_X + PE_DIM)            /* 192 */
#define ROW_CAP   512u                      /* adjacency row stride (u16) */
#define VCAP      512u                      /* visitor list cap (max expected ~180) */
#define NBLK      512
#define NTHR      256

/* workspace layout (bytes) — ~14.5 MiB */
#define OFF_MASKS   0u                                    /* 64 KiB */
#define OFF_DEG     (OFF_MASKS + N_NODES * 16u)           /* 16 KiB */
#define OFF_ADJ     (OFF_DEG + N_NODES * 4u)              /* 4 MiB */
#define OFF_WM      (OFF_ADJ + N_NODES * ROW_CAP * 2u)    /* 5 MiB */
#define OFF_VCNT    (OFF_WM + N_WALKS_TOT * PE_DIM * 2u)  /* 16 KiB */
#define OFF_VLIST   (OFF_VCNT + N_NODES * 4u)             /* 4 MiB */
#define OFF_WNODES  (OFF_VLIST + N_NODES * VCAP * 2u)     /* 40960*8*2 = 640 KiB */

/* ---- threefry2x32 (20 rounds) — cheap high-quality PRF ---- */
__device__ __forceinline__ void tf2x32(uint32_t kk0, uint32_t kk1,
                                       uint32_t x0, uint32_t x1,
                                       uint32_t& o0, uint32_t& o1) {
  const uint32_t kk2 = kk0 ^ kk1 ^ 0x1BD11BDAu;
  x0 += kk0; x1 += kk1;
  auto rnd = [&](int r) {
    x0 += x1;
    x1 = (x1 << r) | (x1 >> (32 - r));
    x1 ^= x0;
  };
  rnd(13); rnd(15); rnd(26); rnd(6);   x0 += kk1; x1 += kk2 + 1u;
  rnd(17); rnd(29); rnd(16); rnd(24);  x0 += kk2; x1 += kk0 + 2u;
  rnd(13); rnd(15); rnd(26); rnd(6);   x0 += kk0; x1 += kk1 + 3u;
  rnd(17); rnd(29); rnd(16); rnd(24);  x0 += kk1; x1 += kk2 + 4u;
  rnd(13); rnd(15); rnd(26); rnd(6);   x0 += kk2; x1 += kk0 + 5u;
  o0 = x0; o1 = x1;
}

/* ---- single cooperative kernel: 512 blocks x 256 threads, 2 blocks/CU ---- */
__global__ void __launch_bounds__(NTHR)
k_fused(const float* __restrict__ x, const float* __restrict__ inc,
        const float* __restrict__ embed, float* __restrict__ out,
        char* __restrict__ ws) {
  __shared__ ulonglong2 sm[N_NODES];           /* 64 KiB: masks / reduce scratch */
  ulonglong2*     masks  = (ulonglong2*)(ws + OFF_MASKS);
  unsigned int*   deg    = (unsigned int*)(ws + OFF_DEG);
  unsigned short* adj    = (unsigned short*)(ws + OFF_ADJ);
  __half*         wm     = (__half*)(ws + OFF_WM);
  unsigned int*   vcnt   = (unsigned int*)(ws + OFF_VCNT);
  unsigned short* vlist  = (unsigned short*)(ws + OFF_VLIST);
  unsigned short* wnodes = (unsigned short*)(ws + OFF_WNODES);

  cg::grid_group grid = cg::this_grid();
  const int tid = threadIdx.x, wid = tid >> 6, lane = tid & 63;
  const int blk = blockIdx.x;
  const int gt = blk * NTHR + tid;            /* global thread  0..131071 */
  const int gw = blk * 4 + wid;               /* global wave    0..2047   */

  /* ---- Phase A: incidence masks (2 nodes per wave) + vcnt zero ---- */
  if (gt < N_NODES) vcnt[gt] = 0u;
#pragma unroll
  for (int r = 0; r < 2; ++r) {
    const int i = gw * 2 + r;
    const float a = inc[i * N_EDGES + lane];
    const float b = inc[i * N_EDGES + 64 + lane];
    const unsigned long long m0 = __ballot(a != 0.f);
    const unsigned long long m1 = __ballot(b != 0.f);
    if (lane == 0) masks[i] = make_ulonglong2(m0, m1);
  }
  grid.sync();

  /* ---- Phase B: adjacency rows + degree (masks staged in LDS) ---- */
  for (int k = tid; k < N_NODES; k += NTHR) sm[k] = masks[k];
  __syncthreads();
#pragma unroll
  for (int r = 0; r < 2; ++r) {
    const int i = blk * 8 + wid * 2 + r;
    const ulonglong2 mi = sm[i];
    unsigned short* row = adj + (unsigned int)i * ROW_CAP;
    unsigned int base = 0;
    for (int g = 0; g < N_NODES / 64; ++g) {
      const int j = g * 64 + lane;
      const ulonglong2 mj = sm[j];
      const bool pred = (((mi.x & mj.x) | (mi.y & mj.y)) != 0ull) && (j != i);
      const unsigned long long bal = __ballot(pred);
      if (pred) {
        const unsigned int off =
            (unsigned int)__popcll(bal & ((1ull << lane) - 1ull));
        const unsigned int pos = base + off;
        if (pos < ROW_CAP) row[pos] = (unsigned short)j;
      }
      base += (unsigned int)__popcll(bal);
    }
    if (lane == 0) deg[i] = (base < ROW_CAP) ? base : ROW_CAP;
  }
  grid.sync();

  /* ---- Phase C1: one walk per THREAD (64 walks/wave in parallel) ---- */
  if (gt < N_WALKS_TOT) {
    const uint32_t w = (uint32_t)gt;
    uint32_t r0, r1, r2, r3;
    tf2x32(0u, 42u, w, 0u, r0, r1);
    tf2x32(0u, 42u, w, 1u, r2, r3);
    const uint32_t n0 = w / NUM_WALKS;
    uint32_t n1, n2, n3, n4, nvalid;
    const unsigned int d0 = deg[n0];
    if (d0 == 0) {
      n1 = n2 = n3 = n4 = n0;
      nvalid = 1u;
    } else {
      uint32_t cur = n0;
      unsigned int d;
      cur = adj[(cur << 9) + (uint32_t)(((uint64_t)r0 * d0) >> 32)]; n1 = cur;
      d = deg[cur];
      cur = adj[(cur << 9) + (uint32_t)(((uint64_t)r1 * d) >> 32)]; n2 = cur;
      d = deg[cur];
      cur = adj[(cur << 9) + (uint32_t)(((uint64_t)r2 * d) >> 32)]; n3 = cur;
      d = deg[cur];
      cur = adj[(cur << 9) + (uint32_t)(((uint64_t)r3 * d) >> 32)]; n4 = cur;
      nvalid = 5u;
    }
    ushort ns[8] = {(unsigned short)n0, (unsigned short)n1, (unsigned short)n2,
                    (unsigned short)n3, (unsigned short)n4,
                    (unsigned short)nvalid, 0, 0};
    *(uint4*)(wnodes + (size_t)w * 8u) = *(const uint4*)ns;
    /* visit records */
    {
      unsigned int slot = atomicAdd(&vcnt[n0], 1u);
      if (slot < VCAP) vlist[n0 * VCAP + slot] = (unsigned short)w;
    }
    if (nvalid == 5u) {
      unsigned int s1 = atomicAdd(&vcnt[n1], 1u);
      if (s1 < VCAP) vlist[n1 * VCAP + s1] = (unsigned short)w;
      unsigned int s2 = atomicAdd(&vcnt[n2], 1u);
      if (s2 < VCAP) vlist[n2 * VCAP + s2] = (unsigned short)w;
      unsigned int s3 = atomicAdd(&vcnt[n3], 1u);
      if (s3 < VCAP) vlist[n3 * VCAP + s3] = (unsigned short)w;
      unsigned int s4 = atomicAdd(&vcnt[n4], 1u);
      if (s4 < VCAP) vlist[n4 * VCAP + s4] = (unsigned short)w;
    }
  }
  grid.sync();

  /* ---- Phase C2: walk means, wave-per-walk (lane == dim), 20/wave ---- */
#pragma unroll 2
  for (int k = 0; k < 20; ++k) {
    const int w = gw * 20 + k;
    const uint4 pk = *(const uint4*)(wnodes + (size_t)w * 8u); /* uniform */
    const uint32_t a = pk.x, b = pk.y, cc = pk.z;
    const uint32_t n0 = a & 0xFFFFu, n1 = a >> 16;
    const uint32_t n2 = b & 0xFFFFu, n3 = b >> 16;
    const uint32_t n4 = cc & 0xFFFFu, nvalid = cc >> 16;
    float s = embed[n0 * PE_DIM + lane];
    if (nvalid == 5u) {
      s += embed[n1 * PE_DIM + lane];
      s += embed[n2 * PE_DIM + lane];
      s += embed[n3 * PE_DIM + lane];
      s += embed[n4 * PE_DIM + lane];
    }
    wm[(size_t)w * PE_DIM + lane] = __float2half(s / (float)nvalid);
  }
  grid.sync();

  /* ---- Phase D: gather visitor means, 8 nodes per block ---- */
  float* red = (float*)sm;                    /* [8][4][64] = 8 KiB */
  const int vbase = blk * 8;
  for (int r = wid; r < 8; r += 4) {          /* x passthrough */
    const int v = vbase + r;
    const float2 xv = ((const float2*)(x + (size_t)v * D_X))[lane];
    ((float2*)(out + (size_t)v * OUT_COLS))[lane] = xv;
  }
  for (int r = 0; r < 8; ++r) {
    const int v = vbase + r;
    unsigned int c = vcnt[v];
    if (c > VCAP) c = VCAP;
    const unsigned short* vl = vlist + (unsigned int)v * VCAP;
    float s = 0.f;
    for (unsigned int base = (unsigned int)wid * 8u; base < c; base += 32u) {
#pragma unroll
      for (int q = 0; q < 8; ++q) {
        const unsigned int idx = base + (unsigned int)q;
        const bool ok = idx < c;
        const unsigned int wwk = ok ? (unsigned int)vl[idx] : (unsigned int)vl[0];
        const float val = __half2float(wm[(size_t)wwk * PE_DIM + lane]);
        s += ok ? val : 0.f;
      }
    }
    red[(r * 4 + wid) * PE_DIM + lane] = s;
  }
  __syncthreads();
#pragma unroll
  for (int rr = 0; rr < 2; ++rr) {
    const int r = wid * 2 + rr;
    const int v = vbase + r;
    unsigned int c = vcnt[v];
    if (c > VCAP) c = VCAP;
    const float t4 = red[(r * 4 + 0) * PE_DIM + lane] +
                     red[(r * 4 + 1) * PE_DIM + lane] +
                     red[(r * 4 + 2) * PE_DIM + lane] +
                     red[(r * 4 + 3) * PE_DIM + lane];
    out[(size_t)v * OUT_COLS + D_X + lane] = c ? t4 / (float)c : 0.f;
  }
}

extern "C" void kernel_launch(void* const* d_in, const int* in_sizes, int n_in,
                              void* d_out, int out_size, void* d_ws, size_t ws_size,
                              hipStream_t stream) {
  const float* x   = (const float*)d_in[0];
  const float* inc = (const float*)d_in[1];
  const float* emb = (const float*)d_in[2];
  float* out = (float*)d_out;
  char* ws = (char*)d_ws;

  void* args[] = {(void*)&x, (void*)&inc, (void*)&emb, (void*)&out, (void*)&ws};
  hipLaunchCooperativeKernel((const void*)k_fused, dim3(NBLK), dim3(NTHR),
                             args, 0, stream);
}

// Round 9
// 80.743 us; speedup vs baseline: 4.2703x; 4.2703x over previous
//
#include <hip/hip_runtime.h>
#include <stdint.h>

#define N_NODES   4096
#define N_EDGES   128
#define D_X       128
#define PE_DIM    64
#define NUM_WALKS 10
#define WALK_LEN  5
#define N_WALKS_TOT (N_NODES * NUM_WALKS)   /* 40960 */
#define OUT_COLS  (D_X + PE_DIM)            /* 192 */
#define ROW_CAP   512u                      /* adjacency row stride (u16) */
#define VCAP      512u                      /* visitor list cap (max expected ~180) */

/* workspace layout (bytes) — ~8.8 MiB */
#define OFF_MASKS   0u                                    /* 64 KiB */
#define OFF_DEG     (OFF_MASKS + N_NODES * 16u)           /* 16 KiB */
#define OFF_ADJ     (OFF_DEG + N_NODES * 4u)              /* 4 MiB */
#define OFF_VCNT    (OFF_ADJ + N_NODES * ROW_CAP * 2u)    /* 16 KiB */
#define OFF_VLIST   (OFF_VCNT + N_NODES * 4u)             /* 4 MiB */
#define OFF_WNODES  (OFF_VLIST + N_NODES * VCAP * 2u)     /* 40960*16 = 640 KiB */

/* ---- threefry2x32 (20 rounds) — cheap high-quality PRF ---- */
__device__ __forceinline__ void tf2x32(uint32_t kk0, uint32_t kk1,
                                       uint32_t x0, uint32_t x1,
                                       uint32_t& o0, uint32_t& o1) {
  const uint32_t kk2 = kk0 ^ kk1 ^ 0x1BD11BDAu;
  x0 += kk0; x1 += kk1;
  auto rnd = [&](int r) {
    x0 += x1;
    x1 = (x1 << r) | (x1 >> (32 - r));
    x1 ^= x0;
  };
  rnd(13); rnd(15); rnd(26); rnd(6);   x0 += kk1; x1 += kk2 + 1u;
  rnd(17); rnd(29); rnd(16); rnd(24);  x0 += kk2; x1 += kk0 + 2u;
  rnd(13); rnd(15); rnd(26); rnd(6);   x0 += kk0; x1 += kk1 + 3u;
  rnd(17); rnd(29); rnd(16); rnd(24);  x0 += kk1; x1 += kk2 + 4u;
  rnd(13); rnd(15); rnd(26); rnd(6);   x0 += kk2; x1 += kk0 + 5u;
  o0 = x0; o1 = x1;
}

/* ---- K1: 128-bit incidence masks (one wave per node) + vcnt zeroing ---- */
__global__ void k_masks(const float* __restrict__ inc,
                        ulonglong2* __restrict__ masks,
                        unsigned int* __restrict__ vcnt) {
  const int wid = threadIdx.x >> 6, lane = threadIdx.x & 63;
  const int i = blockIdx.x * 4 + wid;
  const float a = inc[i * N_EDGES + lane];
  const float b = inc[i * N_EDGES + 64 + lane];
  const unsigned long long m0 = __ballot(a != 0.f);
  const unsigned long long m1 = __ballot(b != 0.f);
  if (lane == 0) {
    masks[i] = make_ulonglong2(m0, m1);
    vcnt[i] = 0u;
  }
}

/* ---- K2: adjacency rows (fixed stride) + degree, masks staged in LDS ---- */
__global__ void __launch_bounds__(512)
k_adj(const ulonglong2* __restrict__ masks,
      unsigned short* __restrict__ adj, unsigned int* __restrict__ deg) {
  __shared__ ulonglong2 sm[N_NODES];
  for (int k = threadIdx.x; k < N_NODES; k += 512) sm[k] = masks[k];
  __syncthreads();
  const int wid = threadIdx.x >> 6, lane = threadIdx.x & 63;
  const int i = blockIdx.x * 8 + wid;
  const ulonglong2 mi = sm[i];
  unsigned short* row = adj + (unsigned int)i * ROW_CAP;
  unsigned int base = 0;
  for (int g = 0; g < N_NODES / 64; ++g) {
    const int j = g * 64 + lane;
    const ulonglong2 mj = sm[j];
    const bool pred = (((mi.x & mj.x) | (mi.y & mj.y)) != 0ull) && (j != i);
    const unsigned long long bal = __ballot(pred);
    if (pred) {
      const unsigned int off =
          (unsigned int)__popcll(bal & ((1ull << lane) - 1ull));
      const unsigned int pos = base + off;
      if (pos < ROW_CAP) row[pos] = (unsigned short)j;
    }
    base += (unsigned int)__popcll(bal);
  }
  if (lane == 0) deg[i] = (base < ROW_CAP) ? base : ROW_CAP;
}

/* ---- K3: one walk per THREAD — all 40960 dependent-load chains run
   concurrently (640 waves), so wall time ~ one chain latency. ---- */
__global__ void __launch_bounds__(64)
k_walk(const unsigned int* __restrict__ deg,
       const unsigned short* __restrict__ adj,
       uint4* __restrict__ wnodes,
       unsigned int* __restrict__ vcnt, unsigned short* __restrict__ vlist) {
  const uint32_t w = blockIdx.x * 64u + threadIdx.x;

  uint32_t r0, r1, r2, r3;
  tf2x32(0u, 42u, w, 0u, r0, r1);
  tf2x32(0u, 42u, w, 1u, r2, r3);

  const uint32_t n0 = w / NUM_WALKS;
  uint32_t n1, n2, n3, n4, nvalid;
  const unsigned int d0 = deg[n0];
  if (d0 == 0) {
    n1 = n2 = n3 = n4 = n0;
    nvalid = 1u;
  } else {
    uint32_t cur = n0;
    unsigned int d;
    cur = adj[(cur << 9) + (uint32_t)(((uint64_t)r0 * d0) >> 32)]; n1 = cur;
    d = deg[cur];
    cur = adj[(cur << 9) + (uint32_t)(((uint64_t)r1 * d) >> 32)]; n2 = cur;
    d = deg[cur];
    cur = adj[(cur << 9) + (uint32_t)(((uint64_t)r2 * d) >> 32)]; n3 = cur;
    d = deg[cur];
    cur = adj[(cur << 9) + (uint32_t)(((uint64_t)r3 * d) >> 32)]; n4 = cur;
    nvalid = 5u;
  }

  uint4 rec;
  rec.x = n0 | (n1 << 16);
  rec.y = n2 | (n3 << 16);
  rec.z = n4 | (nvalid << 16);
  rec.w = 0u;
  wnodes[w] = rec;

  /* visit records */
  unsigned int s0 = atomicAdd(&vcnt[n0], 1u);
  if (s0 < VCAP) vlist[n0 * VCAP + s0] = (unsigned short)w;
  if (nvalid == 5u) {
    unsigned int s1 = atomicAdd(&vcnt[n1], 1u);
    if (s1 < VCAP) vlist[n1 * VCAP + s1] = (unsigned short)w;
    unsigned int s2 = atomicAdd(&vcnt[n2], 1u);
    if (s2 < VCAP) vlist[n2 * VCAP + s2] = (unsigned short)w;
    unsigned int s3 = atomicAdd(&vcnt[n3], 1u);
    if (s3 < VCAP) vlist[n3 * VCAP + s3] = (unsigned short)w;
    unsigned int s4 = atomicAdd(&vcnt[n4], 1u);
    if (s4 < VCAP) vlist[n4 * VCAP + s4] = (unsigned short)w;
  }
}

/* ---- K4: block per node; compute visitor means on the fly from wnodes
   (embed slice is 1 MB -> L2-hot) and reduce; also x passthrough. ---- */
__global__ void __launch_bounds__(256)
k_gather(const uint4* __restrict__ wnodes,
         const unsigned int* __restrict__ vcnt,
         const unsigned short* __restrict__ vlist,
         const float* __restrict__ embed,
         const float* __restrict__ x,
         float* __restrict__ out) {
  __shared__ float red[4][PE_DIM];
  const int wid = threadIdx.x >> 6, lane = threadIdx.x & 63;
  const int v = blockIdx.x;

  /* x passthrough by wave 3 (independent of the reduction) */
  if (wid == 3) {
    const float2 xv = ((const float2*)(x + (size_t)v * D_X))[lane];
    ((float2*)(out + (size_t)v * OUT_COLS))[lane] = xv;
  }

  unsigned int c = vcnt[v];
  if (c > VCAP) c = VCAP;
  const unsigned short* vl = vlist + (unsigned int)v * VCAP;

  float s = 0.f;
  for (unsigned int b = (unsigned int)wid * 4u; b < c; b += 16u) {
#pragma unroll
    for (int q = 0; q < 4; ++q) {
      const unsigned int idx = b + (unsigned int)q;
      const bool ok = idx < c;
      const unsigned int ww = ok ? (unsigned int)vl[idx] : (unsigned int)vl[0];
      const uint4 rec = wnodes[ww];              /* wave-uniform broadcast */
      const uint32_t n0 = rec.x & 0xFFFFu, n1 = rec.x >> 16;
      const uint32_t n2 = rec.y & 0xFFFFu, n3 = rec.y >> 16;
      const uint32_t n4 = rec.z & 0xFFFFu, nv = rec.z >> 16;
      float t = embed[n0 * PE_DIM + lane];
      if (nv == 5u) {                            /* uniform branch per wave */
        t += embed[n1 * PE_DIM + lane];
        t += embed[n2 * PE_DIM + lane];
        t += embed[n3 * PE_DIM + lane];
        t += embed[n4 * PE_DIM + lane];
        t *= 0.2f;
      }
      s += ok ? t : 0.f;
    }
  }
  red[wid][lane] = s;
  __syncthreads();
  if (wid == 0) {
    const float t = red[0][lane] + red[1][lane] + red[2][lane] + red[3][lane];
    out[(size_t)v * OUT_COLS + D_X + lane] = c ? t / (float)c : 0.f;
  }
}

extern "C" void kernel_launch(void* const* d_in, const int* in_sizes, int n_in,
                              void* d_out, int out_size, void* d_ws, size_t ws_size,
                              hipStream_t stream) {
  const float* x   = (const float*)d_in[0];
  const float* inc = (const float*)d_in[1];
  const float* emb = (const float*)d_in[2];
  float* out = (float*)d_out;

  char* ws = (char*)d_ws;
  ulonglong2*     masks  = (ulonglong2*)(ws + OFF_MASKS);
  unsigned int*   deg    = (unsigned int*)(ws + OFF_DEG);
  unsigned short* adj    = (unsigned short*)(ws + OFF_ADJ);
  unsigned int*   vcnt   = (unsigned int*)(ws + OFF_VCNT);
  unsigned short* vlist  = (unsigned short*)(ws + OFF_VLIST);
  uint4*          wnodes = (uint4*)(ws + OFF_WNODES);

  k_masks <<<N_NODES / 4, 256, 0, stream>>>(inc, masks, vcnt);
  k_adj   <<<N_NODES / 8, 512, 0, stream>>>(masks, adj, deg);
  k_walk  <<<N_WALKS_TOT / 64, 64, 0, stream>>>(deg, adj, wnodes, vcnt, vlist);
  k_gather<<<N_NODES, 256, 0, stream>>>(wnodes, vcnt, vlist, emb, x, out);
}